// Round 12
// baseline (256.273 us; speedup 1.0000x reference)
//
#include <hip/hip_runtime.h>
#include <hip/hip_bf16.h>
#include <math.h>

#define SEQ 4096
#define DM  768
#define NH  12
#define HD  64
#define PER ((size_t)NH * SEQ * HD)       // 3,145,728
#define XN  ((size_t)SEQ * DM)
#define WN  ((size_t)DM * DM)

typedef __attribute__((ext_vector_type(8))) short bf16x8;   // MFMA A/B frag
typedef __attribute__((ext_vector_type(4))) short s16x4;
typedef __attribute__((ext_vector_type(4))) float f32x4;    // MFMA C/D frag

#define MFMA(a, b, c) __builtin_amdgcn_mfma_f32_16x16x32_bf16((a), (b), (c), 0, 0, 0)

#if __has_builtin(__builtin_amdgcn_exp2f)
#define EXP2(x) __builtin_amdgcn_exp2f(x)
#else
#define EXP2(x) exp2f(x)
#endif

// XOR-swizzled 64-wide bf16 LDS tile, 16B blocks (conflict-free b128).
#define SWZ(row, blk) (((row) << 6) + ((((blk) ^ ((row) & 7))) << 3))

// fast RTNE fp32->bf16 (finite values only)
__device__ __forceinline__ unsigned short f2b(float f) {
    unsigned int u = __float_as_uint(f);
    u += 0x7FFFu + ((u >> 16) & 1u);
    return (unsigned short)(u >> 16);
}

// ---------------------------------------------------------------------------
// Prep: ONE kernel converts x + 4 weights fp32->bf16 and fills the RoPE table.
// ---------------------------------------------------------------------------
__global__ __launch_bounds__(256) void prep_kernel(
    const float* __restrict__ x,  const float* __restrict__ wq,
    const float* __restrict__ wk, const float* __restrict__ wv,
    const float* __restrict__ wo,
    unsigned short* __restrict__ dstbase, float2* __restrict__ rope)
{
    const float* srcs[5] = {x, wq, wk, wv, wo};
    const size_t n4s[5]  = {XN / 4, WN / 4, WN / 4, WN / 4, WN / 4};
    unsigned short* d = dstbase;
    for (int rg = 0; rg < 5; ++rg) {
        const float4* s4 = (const float4*)srcs[rg];
        s16x4* d4 = (s16x4*)d;
        for (size_t i = (size_t)blockIdx.x * 256 + threadIdx.x; i < n4s[rg];
             i += (size_t)gridDim.x * 256) {
            const float4 v = s4[i];
            s16x4 p;
            p.x = (short)f2b(v.x); p.y = (short)f2b(v.y);
            p.z = (short)f2b(v.z); p.w = (short)f2b(v.w);
            d4[i] = p;
        }
        d += n4s[rg] * 4;
    }
    for (int g = blockIdx.x * 256 + threadIdx.x; g < 131072; g += gridDim.x * 256) {
        const int row = g >> 5, fi = g & 31;
        const float invf = expf(-(float)fi * 0.28782313662425576f);
        float sn, cs;
        sincosf((float)row * invf, &sn, &cs);
        rope[row * 32 + fi] = make_float2(cs, sn);
    }
}

// ---------------------------------------------------------------------------
// K1: FUSED QKV projection. Grid (64, 12): block (s0, h) computes the 64x64
// tiles of Q, K and V for head h in one pass. A-frags (x) loaded DIRECT
// global->VGPR (each feeds 24 MFMAs); W tiles for all 3 matrices
// double-buffered in LDS with register prefetch; one barrier per k-iter.
// Epilogue: Q-RoPE + K-RoPE + V-transpose (LDS reuse). Q pre-scaled
// 0.125*log2(e). Q,K out [h][seq][64]; V out transposed [h][64][seq].
// ---------------------------------------------------------------------------
__global__ __launch_bounds__(256) void qkv_fused(
    const float* __restrict__ x,  const unsigned short* __restrict__ xb,
    const float* __restrict__ Wq, const float* __restrict__ Wk, const float* __restrict__ Wv,
    const unsigned short* __restrict__ Wqb, const unsigned short* __restrict__ Wkb,
    const unsigned short* __restrict__ Wvb,
    const float2* __restrict__ rope,
    unsigned short* __restrict__ Qo, unsigned short* __restrict__ Ko,
    unsigned short* __restrict__ Vo, int fast)
{
    __shared__ __align__(16) unsigned short WshFlat[2 * 3 * 4096];   // 48 KB

    const int t    = threadIdx.x;
    const int w    = t >> 6;
    const int lane = t & 63;
    const int quad = lane >> 4;
    const int l16  = lane & 15;
    const int h    = blockIdx.y;
    const int s0   = blockIdx.x * 64;
    const int n0   = h * 64;
    const int prow = t >> 3, pblk = t & 7;
    const size_t arow = (size_t)(s0 + 16 * w + l16);   // this lane's A row

    const unsigned short* Wb[3] = {Wqb, Wkb, Wvb};
    const float*          Wf[3] = {Wq, Wk, Wv};

    f32x4 acc[3][4];
    #pragma unroll
    for (int rg = 0; rg < 3; ++rg)
        #pragma unroll
        for (int nt = 0; nt < 4; ++nt) acc[rg][nt] = (f32x4){0, 0, 0, 0};

    // ---- stage W chunk 0 into buffer 0 ----
    if (fast) {
        #pragma unroll
        for (int rg = 0; rg < 3; ++rg) {
            *(bf16x8*)&WshFlat[rg * 4096 + SWZ(prow, pblk)] =
                *(const bf16x8*)&Wb[rg][(size_t)(n0 + prow) * DM + pblk * 8];
            *(bf16x8*)&WshFlat[rg * 4096 + SWZ(prow + 32, pblk)] =
                *(const bf16x8*)&Wb[rg][(size_t)(n0 + prow + 32) * DM + pblk * 8];
        }
    } else {
        for (int rg = 0; rg < 3; ++rg)
            for (int e = t; e < 1024; e += 256) {
                const int row = e >> 4, c4 = e & 15;
                const float4 wv4 = *(const float4*)&Wf[rg][(size_t)(n0 + row) * DM + c4 * 4];
                s16x4 pw; pw.x = (short)f2b(wv4.x); pw.y = (short)f2b(wv4.y);
                pw.z = (short)f2b(wv4.z); pw.w = (short)f2b(wv4.w);
                *(s16x4*)&WshFlat[rg * 4096 + SWZ(row, c4 >> 1) + (c4 & 1) * 4] = pw;
            }
    }

    // ---- A-frags for chunk 0 ----
    bf16x8 aX[2];
    if (fast) {
        aX[0] = *(const bf16x8*)&xb[arow * DM + 8 * quad];
        aX[1] = *(const bf16x8*)&xb[arow * DM + 32 + 8 * quad];
    }
    __syncthreads();

    for (int kt = 0; kt < 12; ++kt) {
        bf16x8 wpre[6], aXn[2];
        if (fast && kt < 11) {                 // prefetch next chunk EARLY
            const int k0n = (kt + 1) * 64;
            #pragma unroll
            for (int rg = 0; rg < 3; ++rg) {
                wpre[2 * rg] =
                    *(const bf16x8*)&Wb[rg][(size_t)(n0 + prow) * DM + k0n + pblk * 8];
                wpre[2 * rg + 1] =
                    *(const bf16x8*)&Wb[rg][(size_t)(n0 + prow + 32) * DM + k0n + pblk * 8];
            }
            aXn[0] = *(const bf16x8*)&xb[arow * DM + k0n + 8 * quad];
            aXn[1] = *(const bf16x8*)&xb[arow * DM + k0n + 32 + 8 * quad];
        }
        if (!fast) {                           // fallback: fp32 A loads in-loop
            #pragma unroll
            for (int hh = 0; hh < 2; ++hh) {
                const float* p = &x[arow * DM + kt * 64 + 32 * hh + 8 * quad];
                const float4 v0 = *(const float4*)p;
                const float4 v1 = *(const float4*)(p + 4);
                bf16x8 r;
                r[0] = (short)f2b(v0.x); r[1] = (short)f2b(v0.y);
                r[2] = (short)f2b(v0.z); r[3] = (short)f2b(v0.w);
                r[4] = (short)f2b(v1.x); r[5] = (short)f2b(v1.y);
                r[6] = (short)f2b(v1.z); r[7] = (short)f2b(v1.w);
                aX[hh] = r;
            }
        }

        const unsigned short* Wc = &WshFlat[(kt & 1) * 3 * 4096];
        #pragma unroll
        for (int rg = 0; rg < 3; ++rg)
            #pragma unroll
            for (int nt = 0; nt < 4; ++nt) {
                const bf16x8 b0 = *(const bf16x8*)&Wc[rg * 4096 + SWZ(16 * nt + l16, quad)];
                const bf16x8 b1 = *(const bf16x8*)&Wc[rg * 4096 + SWZ(16 * nt + l16, 4 + quad)];
                acc[rg][nt] = MFMA(aX[0], b0, acc[rg][nt]);
                acc[rg][nt] = MFMA(aX[1], b1, acc[rg][nt]);
            }

        if (kt < 11) {
            unsigned short* Wn = &WshFlat[((kt + 1) & 1) * 3 * 4096];
            if (fast) {                        // vmcnt wait lands here
                #pragma unroll
                for (int rg = 0; rg < 3; ++rg) {
                    *(bf16x8*)&Wn[rg * 4096 + SWZ(prow, pblk)]      = wpre[2 * rg];
                    *(bf16x8*)&Wn[rg * 4096 + SWZ(prow + 32, pblk)] = wpre[2 * rg + 1];
                }
                aX[0] = aXn[0]; aX[1] = aXn[1];
            } else {
                const int k0n = (kt + 1) * 64;
                for (int rg = 0; rg < 3; ++rg)
                    for (int e = t; e < 1024; e += 256) {
                        const int row = e >> 4, c4 = e & 15;
                        const float4 wv4 =
                            *(const float4*)&Wf[rg][(size_t)(n0 + row) * DM + k0n + c4 * 4];
                        s16x4 pw; pw.x = (short)f2b(wv4.x); pw.y = (short)f2b(wv4.y);
                        pw.z = (short)f2b(wv4.z); pw.w = (short)f2b(wv4.w);
                        *(s16x4*)&Wn[rg * 4096 + SWZ(row, c4 >> 1) + (c4 & 1) * 4] = pw;
                    }
            }
        }
        __syncthreads();
    }

    // ---- epilogue ----
    const size_t headoff = (size_t)h * SEQ * HD;

    // Q (rg 0) and K (rg 1): RoPE in registers via shfl_xor(1).
    #pragma unroll
    for (int rg = 0; rg < 2; ++rg) {
        unsigned short* dst = (rg == 0) ? Qo : Ko;
        const float qsc = (rg == 0) ? 0.18033688011112042f : 1.0f;   // 0.125*log2e
        #pragma unroll
        for (int nt = 0; nt < 4; ++nt)
            #pragma unroll
            for (int r = 0; r < 4; ++r) {
                const int srow = s0 + 16 * w + quad * 4 + r;
                const int d  = nt * 16 + l16;
                const int fi = d >> 1;
                const float own = acc[rg][nt][r] * qsc;
                const float oth = __shfl_xor(own, 1);
                float cs, sn;
                if (fast) {
                    const float2 t2 = rope[srow * 32 + fi];
                    cs = t2.x; sn = t2.y;
                } else {
                    const float invf = expf(-(float)fi * 0.28782313662425576f);
                    sincosf((float)srow * invf, &sn, &cs);
                }
                const float val = (d & 1) ? (oth * sn + own * cs)
                                          : (own * cs - oth * sn);
                dst[headoff + (size_t)srow * HD + ((d & 1) ? 32 : 0) + fi] = f2b(val);
            }
    }

    // V (rg 2): transpose via LDS (reuse W buffers; loop ended with barrier).
    unsigned short* VL = WshFlat;          // 64 x 66
    #pragma unroll
    for (int nt = 0; nt < 4; ++nt)
        #pragma unroll
        for (int r = 0; r < 4; ++r)
            VL[(nt * 16 + l16) * 66 + 16 * w + quad * 4 + r] = f2b(acc[2][nt][r]);
    __syncthreads();
    for (int e = t; e < 2048; e += 256) {
        const int d = e >> 5, sp = e & 31;
        const unsigned int v = (unsigned int)VL[d * 66 + 2 * sp] |
                               ((unsigned int)VL[d * 66 + 2 * sp + 1] << 16);
        *(unsigned int*)&Vo[headoff + (size_t)d * SEQ + s0 + 2 * sp] = v;
    }
}

// ---------------------------------------------------------------------------
// K2: causal flash attention — round 10 version (measured best, 87 us).
// Split-keys across waves AND blocks; LDS-staged K/V double buffer;
// fp32 [q][d] partials for the long tiles.
// ---------------------------------------------------------------------------
__global__ __launch_bounds__(256, 2) void attn_mfma(
    const unsigned short* __restrict__ Q,    // [h][seq][64], pre-scaled
    const unsigned short* __restrict__ K,    // [h][seq][64]
    const unsigned short* __restrict__ V,    // [h][64][seq]  (transposed)
    unsigned short* __restrict__ O,          // [4096][768]
    float* __restrict__ Part)                // [384][2][4160] fp32 partials
{
    __shared__ __align__(16) unsigned char SM[53248];
    unsigned short* Kst = (unsigned short*)SM;             // 128x64 SWZ, 16KB
    unsigned short* Vt  = (unsigned short*)(SM + 16384);   // 64x128 SWZ16, 16KB
    unsigned short* Ps  = (unsigned short*)(SM + 32768);   // 4 strips 64x40, 20KB
    float* ACC  = (float*)SM;
    float* ACC2 = (float*)(SM + 32768);
    float* Lx   = (float*)(SM + 51200);

    const int h  = blockIdx.y;
    const int xx = blockIdx.x;
    int i, kstart, nch, domask, partial, pslice;
    if (gridDim.x == 96) {
        if (xx < 64) {
            i = 63 - xx; kstart = 0;
            const int full = ((i * 64 + 63) >> 7) + 1;
            nch = full < 16 ? full : 16;
            domask  = (i <= 31);
            partial = (i >= 32); pslice = 0;
        } else {
            i = 127 - xx; kstart = 2048;
            nch = ((i * 64 + 63 - 2048) >> 7) + 1;
            domask = 1; partial = 1; pslice = 1;
        }
    } else {
        i = 63 - xx; kstart = 0;
        nch = ((i * 64 + 63) >> 7) + 1;
        domask = 1; partial = 0; pslice = 0;
    }
    const int q0 = i * 64;

    const int t    = threadIdx.x;
    const int w    = t >> 6;
    const int lane = t & 63;
    const int quad = lane >> 4;
    const int l16  = lane & 15;
    const size_t headoff = (size_t)h * SEQ * HD;

    // ---- stage Q (SWZ64) into Kst, read A-frags for all 64 rows ----
    for (int e = t; e < 512; e += 256) {
        const int row = e >> 3, bp = e & 7, blk = bp ^ (row & 7);
        *(bf16x8*)&Kst[row * 64 + bp * 8] =
            *(const bf16x8*)&Q[headoff + (size_t)(q0 + row) * HD + blk * 8];
    }
    __syncthreads();
    bf16x8 aQ[4][2];
    #pragma unroll
    for (int qt = 0; qt < 4; ++qt)
        #pragma unroll
        for (int hh = 0; hh < 2; ++hh)
            aQ[qt][hh] = *(const bf16x8*)&Kst[SWZ(16 * qt + l16, 4 * hh + quad)];
    __syncthreads();

    // ---- stage chunk 0 (keys kstart..kstart+127) ----
    bf16x8 kreg[4], vreg[4];
    #pragma unroll
    for (int ii = 0; ii < 4; ++ii) {
        const int e = t + ii * 256, row = e >> 3, bp = e & 7, blk = bp ^ (row & 7);
        kreg[ii] = *(const bf16x8*)&K[headoff + (size_t)(kstart + row) * HD + blk * 8];
    }
    #pragma unroll
    for (int ii = 0; ii < 4; ++ii) {
        const int e = t + ii * 256, row = e >> 4, bp = e & 15, blk = bp ^ (row & 15);
        vreg[ii] = *(const bf16x8*)&V[headoff + (size_t)row * SEQ + kstart + blk * 8];
    }
    #pragma unroll
    for (int ii = 0; ii < 4; ++ii) {
        const int e = t + ii * 256, row = e >> 3, bp = e & 7;
        *(bf16x8*)&Kst[row * 64 + bp * 8] = kreg[ii];
    }
    #pragma unroll
    for (int ii = 0; ii < 4; ++ii) {
        const int e = t + ii * 256, row = e >> 4, bp = e & 15;
        *(bf16x8*)&Vt[row * 128 + bp * 8] = vreg[ii];
    }
    __syncthreads();

    bf16x8 ones;
    #pragma unroll
    for (int ii = 0; ii < 8; ++ii) ones[ii] = (short)0x3F80;

    f32x4 oT[4][4];
    #pragma unroll
    for (int dt = 0; dt < 4; ++dt)
        #pragma unroll
        for (int qt = 0; qt < 4; ++qt) oT[dt][qt] = (f32x4){0,0,0,0};
    f32x4 lT[4] = {{0,0,0,0},{0,0,0,0},{0,0,0,0},{0,0,0,0}};

    unsigned short* usp = Ps + w * 2560;

    for (int c = 0; c < nch; ++c) {
        const int k0 = kstart + c * 128;

        f32x4 sC[4][2];
        #pragma unroll
        for (int qt = 0; qt < 4; ++qt)
            #pragma unroll
            for (int kt = 0; kt < 2; ++kt) sC[qt][kt] = (f32x4){0,0,0,0};
        #pragma unroll
        for (int kt = 0; kt < 2; ++kt) {
            const int krow = 32 * w + 16 * kt + l16;
            #pragma unroll
            for (int hh = 0; hh < 2; ++hh) {
                const bf16x8 bK = *(const bf16x8*)&Kst[SWZ(krow, 4 * hh + quad)];
                #pragma unroll
                for (int qt = 0; qt < 4; ++qt)
                    sC[qt][kt] = MFMA(aQ[qt][hh], bK, sC[qt][kt]);
            }
        }

        if (c < nch - 1) {
            const int kn = k0 + 128;
            #pragma unroll
            for (int ii = 0; ii < 4; ++ii) {
                const int e = t + ii * 256, row = e >> 3, bp = e & 7, blk = bp ^ (row & 7);
                kreg[ii] = *(const bf16x8*)&K[headoff + (size_t)(kn + row) * HD + blk * 8];
            }
            #pragma unroll
            for (int ii = 0; ii < 4; ++ii) {
                const int e = t + ii * 256, row = e >> 4, bp = e & 15, blk = bp ^ (row & 15);
                vreg[ii] = *(const bf16x8*)&V[headoff + (size_t)row * SEQ + kn + blk * 8];
            }
        }

        if (domask && c == nch - 1) {
            #pragma unroll
            for (int kt = 0; kt < 2; ++kt) {
                const int key = k0 + 32 * w + 16 * kt + l16;
                #pragma unroll
                for (int qt = 0; qt < 4; ++qt)
                    #pragma unroll
                    for (int r = 0; r < 4; ++r)
                        if (key > q0 + 16 * qt + 4 * quad + r) sC[qt][kt][r] = -1e30f;
            }
        }

        #pragma unroll
        for (int qt = 0; qt < 4; ++qt)
            #pragma unroll
            for (int kt = 0; kt < 2; ++kt)
                #pragma unroll
                for (int r = 0; r < 4; ++r)
                    usp[(16 * qt + 4 * quad + r) * 40 + 16 * kt + l16] =
                        f2b(EXP2(sC[qt][kt][r]));
        asm volatile("s_waitcnt lgkmcnt(0)" ::: "memory");

        bf16x8 aV[4];
        #pragma unroll
        for (int dt = 0; dt < 4; ++dt) {
            const int row = 16 * dt + l16;
            aV[dt] = *(const bf16x8*)&Vt[row * 128 + (((4 * w + quad) ^ (row & 15)) << 3)];
        }
        #pragma unroll
        for (int qt = 0; qt < 4; ++qt) {
            const bf16x8 bP = *(const bf16x8*)&usp[(16 * qt + l16) * 40 + quad * 8];
            lT[qt] = MFMA(ones, bP, lT[qt]);
            #pragma unroll
            for (int dt = 0; dt < 4; ++dt)
                oT[dt][qt] = MFMA(aV[dt], bP, oT[dt][qt]);
        }

        __syncthreads();
        if (c < nch - 1) {
            #pragma unroll
            for (int ii = 0; ii < 4; ++ii) {
                const int e = t + ii * 256, row = e >> 3, bp = e & 7;
                *(bf16x8*)&Kst[row * 64 + bp * 8] = kreg[ii];
            }
            #pragma unroll
            for (int ii = 0; ii < 4; ++ii) {
                const int e = t + ii * 256, row = e >> 4, bp = e & 15;
                *(bf16x8*)&Vt[row * 128 + bp * 8] = vreg[ii];
            }
        }
        __syncthreads();
    }

    // ---- cross-wave reduction of O^T and l ----
    if (w != 0 && quad == 0) {
        #pragma unroll
        for (int qt = 0; qt < 4; ++qt)
            Lx[w * 64 + 16 * qt + l16] = lT[qt][0];
    }
    if (w == 1) {
        #pragma unroll
        for (int dt = 0; dt < 4; ++dt)
            #pragma unroll
            for (int qt = 0; qt < 4; ++qt)
                *(f32x4*)&ACC[(16 * qt + l16) * 72 + 16 * dt + 4 * quad] = oT[dt][qt];
    }
    __syncthreads();
    if (w == 0) {
        #pragma unroll
        for (int dt = 0; dt < 4; ++dt)
            #pragma unroll
            for (int qt = 0; qt < 4; ++qt)
                oT[dt][qt] += *(const f32x4*)&ACC[(16 * qt + l16) * 72 + 16 * dt + 4 * quad];
    }
    if (w == 2) {
        #pragma unroll
        for (int dt = 0; dt < 4; ++dt)
            #pragma unroll
            for (int qt = 0; qt < 4; ++qt)
                *(f32x4*)&ACC2[(16 * qt + l16) * 72 + 16 * dt + 4 * quad] = oT[dt][qt];
    }
    __syncthreads();
    if (w == 0) {
        #pragma unroll
        for (int dt = 0; dt < 4; ++dt)
            #pragma unroll
            for (int qt = 0; qt < 4; ++qt)
                oT[dt][qt] += *(const f32x4*)&ACC2[(16 * qt + l16) * 72 + 16 * dt + 4 * quad];
    }
    if (w == 3) {
        #pragma unroll
        for (int dt = 0; dt < 4; ++dt)
            #pragma unroll
            for (int qt = 0; qt < 4; ++qt)
                *(f32x4*)&ACC[(16 * qt + l16) * 72 + 16 * dt + 4 * quad] = oT[dt][qt];
    }
    __syncthreads();
    if (w == 0) {
        float ls[4];
        #pragma unroll
        for (int qt = 0; qt < 4; ++qt) {
            #pragma unroll
            for (int dt = 0; dt < 4; ++dt)
                oT[dt][qt] += *(const f32x4*)&ACC[(16 * qt + l16) * 72 + 16 * dt + 4 * quad];
            ls[qt] = lT[qt][0] + Lx[64 + 16 * qt + l16] +
                     Lx[128 + 16 * qt + l16] + Lx[192 + 16 * qt + l16];
        }
        if (!partial) {
            #pragma unroll
            for (int qt = 0; qt < 4; ++qt) {
                const float inv = 1.0f / ls[qt];
                const size_t rowoff = (size_t)(q0 + 16 * qt + l16) * DM + h * HD;
                #pragma unroll
                for (int dt = 0; dt < 4; ++dt) {
                    ushort4 u;
                    u.x = f2b(oT[dt][qt][0] * inv);
                    u.y = f2b(oT[dt][qt][1] * inv);
                    u.z = f2b(oT[dt][qt][2] * inv);
                    u.w = f2b(oT[dt][qt][3] * inv);
                    *(ushort4*)&O[rowoff + 16 * dt + 4 * quad] = u;
                }
            }
        } else {
            // [q][d] layout: oT[dt][qt][r] = O[q=16qt+l16][d=16dt+4quad+r]
            float* P = Part + (size_t)(((i - 32) * 12 + h) * 2 + pslice) * 4160;
            #pragma unroll
            for (int dt = 0; dt < 4; ++dt)
                #pragma unroll
                for (int qt = 0; qt < 4; ++qt)
                    *(f32x4*)&P[(16 * qt + l16) * 64 + 16 * dt + 4 * quad] = oT[dt][qt];
            if (quad == 0) {
                #pragma unroll
                for (int qt = 0; qt < 4; ++qt)
                    P[4096 + 16 * qt + l16] = ls[qt];
            }
        }
    }
}

// ---------------------------------------------------------------------------
// K2b: combine the two key-slices for q-tiles 32..63 — unchanged from r10.
// ---------------------------------------------------------------------------
__global__ __launch_bounds__(256) void reduce_attn(
    const float* __restrict__ Part, unsigned short* __restrict__ O)
{
    const int b  = blockIdx.x;
    const int i  = 32 + b / 12, h = b % 12;
    const int q0 = i * 64;
    const float* P0 = Part + (size_t)(b * 2 + 0) * 4160;
    const float* P1 = Part + (size_t)(b * 2 + 1) * 4160;
    __shared__ float linv[64];
    const int t = threadIdx.x;
    if (t < 64) linv[t] = 1.0f / (P0[4096 + t] + P1[4096 + t]);
    __syncthreads();
    for (int idx = t; idx < 4096; idx += 256) {
        const int q = idx >> 6, d = idx & 63;
        const float v = (P0[q * 64 + d] + P1[q * 64 + d]) * linv[q];
        O[(size_t)(q0 + q) * DM + h * HD + d] = f2b(v);
    }
}

// ---------------------------------------------------------------------------
// K3: output projection out = A @ Wo.T + bo (MFMA) — unchanged from round 10.
// ---------------------------------------------------------------------------
__global__ __launch_bounds__(256) void proj_mfma(
    const unsigned short* __restrict__ A,
    const float* __restrict__ Wo, const unsigned short* __restrict__ Wob,
    const float* __restrict__ bo,
    float* __restrict__ out, int fast)
{
    __shared__ __align__(16) unsigned short Xs[2][4096];
    __shared__ __align__(16) unsigned short Ws[2][4096];

    const int t    = threadIdx.x;
    const int w    = t >> 6;
    const int lane = t & 63;
    const int quad = lane >> 4;
    const int l16  = lane & 15;
    const int s0 = blockIdx.x * 64;
    const int n0 = blockIdx.y * 64;
    const int prow = t >> 3, pblk = t & 7;

    f32x4 acc[4] = {{0,0,0,0},{0,0,0,0},{0,0,0,0},{0,0,0,0}};

    bf16x8 ar0, ar1, wr0, wr1;
    ar0 = *(const bf16x8*)&A[(size_t)(s0 + prow) * DM + pblk * 8];
    ar1 = *(const bf16x8*)&A[(size_t)(s0 + prow + 32) * DM + pblk * 8];
    *(bf16x8*)&Xs[0][SWZ(prow, pblk)]      = ar0;
    *(bf16x8*)&Xs[0][SWZ(prow + 32, pblk)] = ar1;
    if (fast) {
        wr0 = *(const bf16x8*)&Wob[(size_t)(n0 + prow) * DM + pblk * 8];
        wr1 = *(const bf16x8*)&Wob[(size_t)(n0 + prow + 32) * DM + pblk * 8];
        *(bf16x8*)&Ws[0][SWZ(prow, pblk)]      = wr0;
        *(bf16x8*)&Ws[0][SWZ(prow + 32, pblk)] = wr1;
    } else {
        for (int e = t; e < 1024; e += 256) {
            const int row = e >> 4, c4 = e & 15;
            const float4 wv = *(const float4*)&Wo[(size_t)(n0 + row) * DM + c4 * 4];
            s16x4 pw; pw.x = (short)f2b(wv.x); pw.y = (short)f2b(wv.y);
            pw.z = (short)f2b(wv.z); pw.w = (short)f2b(wv.w);
            *(s16x4*)&Ws[0][SWZ(row, c4 >> 1) + (c4 & 1) * 4] = pw;
        }
    }
    __syncthreads();

    for (int kt = 0; kt < 12; ++kt) {
        const unsigned short* Xb  = Xs[kt & 1];
        const unsigned short* Wbt = Ws[kt & 1];
        if (kt < 11) {
            const int k0 = (kt + 1) * 64;
            ar0 = *(const bf16x8*)&A[(size_t)(s0 + prow) * DM + k0 + pblk * 8];
            ar1 = *(const bf16x8*)&A[(size_t)(s0 + prow + 32) * DM + k0 + pblk * 8];
            if (fast) {
                wr0 = *(const bf16x8*)&Wob[(size_t)(n0 + prow) * DM + k0 + pblk * 8];
                wr1 = *(const bf16x8*)&Wob[(size_t)(n0 + prow + 32) * DM + k0 + pblk * 8];
            }
        }
        const bf16x8 a0 = *(const bf16x8*)&Xb[SWZ(16 * w + l16, quad)];
        const bf16x8 a1 = *(const bf16x8*)&Xb[SWZ(16 * w + l16, 4 + quad)];
        #pragma unroll
        for (int nt = 0; nt < 4; ++nt) {
            const bf16x8 b0 = *(const bf16x8*)&Wbt[SWZ(16 * nt + l16, quad)];
            const bf16x8 b1 = *(const bf16x8*)&Wbt[SWZ(16 * nt + l16, 4 + quad)];
            acc[nt] = MFMA(a0, b0, acc[nt]);
            acc[nt] = MFMA(a1, b1, acc[nt]);
        }
        if (kt < 11) {
            const int nb = (kt + 1) & 1;
            *(bf16x8*)&Xs[nb][SWZ(prow, pblk)]      = ar0;
            *(bf16x8*)&Xs[nb][SWZ(prow + 32, pblk)] = ar1;
            if (fast) {
                *(bf16x8*)&Ws[nb][SWZ(prow, pblk)]      = wr0;
                *(bf16x8*)&Ws[nb][SWZ(prow + 32, pblk)] = wr1;
            } else {
                const int k0 = (kt + 1) * 64;
                for (int e = t; e < 1024; e += 256) {
                    const int row = e >> 4, c4 = e & 15;
                    const float4 wv = *(const float4*)&Wo[(size_t)(n0 + row) * DM + k0 + c4 * 4];
                    s16x4 pw; pw.x = (short)f2b(wv.x); pw.y = (short)f2b(wv.y);
                    pw.z = (short)f2b(wv.z); pw.w = (short)f2b(wv.w);
                    *(s16x4*)&Ws[nb][SWZ(row, c4 >> 1) + (c4 & 1) * 4] = pw;
                }
            }
        }
        __syncthreads();
    }

    #pragma unroll
    for (int nt = 0; nt < 4; ++nt)
        #pragma unroll
        for (int r = 0; r < 4; ++r) {
            const int srow = s0 + 16 * w + quad * 4 + r;
            const int n    = n0 + nt * 16 + l16;
            out[(size_t)srow * DM + n] = acc[nt][r] + bo[n];
        }
}

// ---------------------------------------------------------------------------
extern "C" void kernel_launch(void* const* d_in, const int* in_sizes, int n_in,
                              void* d_out, int out_size, void* d_ws, size_t ws_size,
                              hipStream_t stream) {
    const float* x  = (const float*)d_in[0];
    const float* Wq = (const float*)d_in[2];
    const float* Wk = (const float*)d_in[3];
    const float* Wv = (const float*)d_in[4];
    const float* Wo = (const float*)d_in[5];
    const float* bo = (const float*)d_in[6];
    float* out = (float*)d_out;

    unsigned short* U  = (unsigned short*)d_ws;
    unsigned short* Qw = U;
    unsigned short* Kw = U + PER;
    unsigned short* Vw = U + 2 * PER;    // transposed [h][64][seq]
    unsigned short* Ow = U + 3 * PER;    // [4096][768]
    unsigned short* xb  = U + 4 * PER;
    unsigned short* Wqb = xb + XN;
    unsigned short* Wkb = Wqb + WN;
    unsigned short* Wvb = Wkb + WN;
    unsigned short* Wob = Wvb + WN;
    float2* rope = (float2*)(Wob + WN);  // [4096][32]
    float*  part = (float*)(rope + 4096 * 32);   // [384][2][4160] fp32
    const size_t need  = (char*)part - (char*)d_ws;
    const size_t need2 = need + (size_t)384 * 2 * 4160 * 4;
    const int fast  = (ws_size >= need)  ? 1 : 0;
    const int split = (ws_size >= need2) ? 1 : 0;

    if (fast)
        prep_kernel<<<1024, 256, 0, stream>>>(x, Wq, Wk, Wv, Wo, xb, rope);
    qkv_fused<<<dim3(SEQ / 64, NH), 256, 0, stream>>>(
        x, xb, Wq, Wk, Wv, Wqb, Wkb, Wvb, rope, Qw, Kw, Vw, fast);
    if (split) {
        attn_mfma<<<dim3(96, NH), 256, 0, stream>>>(Qw, Kw, Vw, Ow, part);
        reduce_attn<<<dim3(384), 256, 0, stream>>>(part, Ow);
    } else {
        attn_mfma<<<dim3(64, NH), 256, 0, stream>>>(Qw, Kw, Vw, Ow, part);
    }
    proj_mfma<<<dim3(SEQ / 64, DM / 64), 256, 0, stream>>>(Ow, Wo, Wob, bo, out, fast);
}

// Round 13
// 246.505 us; speedup vs baseline: 1.0396x; 1.0396x over previous
//
#include <hip/hip_runtime.h>
#include <hip/hip_bf16.h>
#include <math.h>

#define SEQ 4096
#define DM  768
#define NH  12
#define HD  64
#define PER ((size_t)NH * SEQ * HD)       // 3,145,728
#define XN  ((size_t)SEQ * DM)
#define WN  ((size_t)DM * DM)

typedef __attribute__((ext_vector_type(8))) short bf16x8;   // MFMA A/B frag
typedef __attribute__((ext_vector_type(4))) short s16x4;
typedef __attribute__((ext_vector_type(4))) float f32x4;    // MFMA C/D frag

#define MFMA(a, b, c) __builtin_amdgcn_mfma_f32_16x16x32_bf16((a), (b), (c), 0, 0, 0)

#if __has_builtin(__builtin_amdgcn_exp2f)
#define EXP2(x) __builtin_amdgcn_exp2f(x)
#else
#define EXP2(x) exp2f(x)
#endif

// XOR-swizzled bf16 LDS tile (64-wide rows), 16B blocks, conflict-free b128.
#define SWZ(row, blk) (((row) << 6) + ((((blk) ^ ((row) & 7))) << 3))

// fast RTNE fp32->bf16 (finite values only)
__device__ __forceinline__ unsigned short f2b(float f) {
    unsigned int u = __float_as_uint(f);
    u += 0x7FFFu + ((u >> 16) & 1u);
    return (unsigned short)(u >> 16);
}

// ---------------------------------------------------------------------------
// Prep: converts x + 4 weights fp32->bf16 and fills the RoPE table.
// ---------------------------------------------------------------------------
__global__ __launch_bounds__(256) void prep_kernel(
    const float* __restrict__ x,  const float* __restrict__ wq,
    const float* __restrict__ wk, const float* __restrict__ wv,
    const float* __restrict__ wo,
    unsigned short* __restrict__ dstbase, float2* __restrict__ rope)
{
    const float* srcs[5] = {x, wq, wk, wv, wo};
    const size_t n4s[5]  = {XN / 4, WN / 4, WN / 4, WN / 4, WN / 4};
    unsigned short* d = dstbase;
    for (int rg = 0; rg < 5; ++rg) {
        const float4* s4 = (const float4*)srcs[rg];
        s16x4* d4 = (s16x4*)d;
        for (size_t i = (size_t)blockIdx.x * 256 + threadIdx.x; i < n4s[rg];
             i += (size_t)gridDim.x * 256) {
            const float4 v = s4[i];
            s16x4 p;
            p.x = (short)f2b(v.x); p.y = (short)f2b(v.y);
            p.z = (short)f2b(v.z); p.w = (short)f2b(v.w);
            d4[i] = p;
        }
        d += n4s[rg] * 4;
    }
    for (int g = blockIdx.x * 256 + threadIdx.x; g < 131072; g += gridDim.x * 256) {
        const int row = g >> 5, fi = g & 31;
        const float invf = expf(-(float)fi * 0.28782313662425576f);
        float sn, cs;
        sincosf((float)row * invf, &sn, &cs);
        rope[row * 32 + fi] = make_float2(cs, sn);
    }
}

// ---------------------------------------------------------------------------
// K1: QKV projection with 128x128 output tiles (m93-shaped). Grid (32, 18):
// y = region*6 + ntile (region 0=Q,1=K,2=V; ntile covers cols n0..n0+127 =
// heads 2*ntile, 2*ntile+1). Wave w owns the 64x64 quadrant (rows 64*(w&1),
// cols 64*(w>>1)). Per k-iter: 32 MFMA vs 16 ds_read + 8 ds_write per wave.
// r10 prefetch pipeline: global loads issued at iter top, ds_write after
// compute, one barrier/iter. Q pre-scaled 0.125*log2(e); RoPE via shfl_xor;
// V written transposed [h][64][seq].
// ---------------------------------------------------------------------------
__global__ __launch_bounds__(256) void qkv128(
    const float* __restrict__ x,  const unsigned short* __restrict__ xb,
    const float* __restrict__ Wq, const float* __restrict__ Wk, const float* __restrict__ Wv,
    const unsigned short* __restrict__ Wqb, const unsigned short* __restrict__ Wkb,
    const unsigned short* __restrict__ Wvb,
    const float2* __restrict__ rope,
    unsigned short* __restrict__ Qo, unsigned short* __restrict__ Ko,
    unsigned short* __restrict__ Vo, int fast)
{
    __shared__ __align__(16) unsigned short SMEM[32768];   // 64 KB
    unsigned short* At0 = SMEM;              // A dbuf: 2 x 128x64
    unsigned short* At1 = SMEM + 8192;
    unsigned short* Bt0 = SMEM + 16384;      // B dbuf
    unsigned short* Bt1 = SMEM + 24576;

    const int t    = threadIdx.x;
    const int w    = t >> 6;
    const int lane = t & 63;
    const int quad = lane >> 4;
    const int l16  = lane & 15;
    const int region = blockIdx.y / 6;
    const int ntile  = blockIdx.y % 6;
    const int n0 = ntile * 128;
    const int s0 = blockIdx.x * 128;
    const int m0  = 64 * (w & 1);
    const int nn0 = 64 * (w >> 1);

    const unsigned short* Wb = (region == 0) ? Wqb : (region == 1) ? Wkb : Wvb;
    const float*          Wf = (region == 0) ? Wq  : (region == 1) ? Wk  : Wv;

    f32x4 acc[4][4];
    #pragma unroll
    for (int i = 0; i < 4; ++i)
        #pragma unroll
        for (int j = 0; j < 4; ++j) acc[i][j] = (f32x4){0, 0, 0, 0};

    bf16x8 areg[4], breg[4];
    // ---- stage chunk 0 ----
    if (fast) {
        #pragma unroll
        for (int i = 0; i < 4; ++i) {
            const int s = t + i * 256, row = s >> 3, bp = s & 7, blk = bp ^ (row & 7);
            areg[i] = *(const bf16x8*)&xb[(size_t)(s0 + row) * DM + blk * 8];
            breg[i] = *(const bf16x8*)&Wb[(size_t)(n0 + row) * DM + blk * 8];
        }
        #pragma unroll
        for (int i = 0; i < 4; ++i) {
            const int s = t + i * 256, row = s >> 3, bp = s & 7;
            *(bf16x8*)&At0[row * 64 + bp * 8] = areg[i];
            *(bf16x8*)&Bt0[row * 64 + bp * 8] = breg[i];
        }
    } else {
        for (int e = t; e < 2048; e += 256) {
            const int row = e >> 4, c4 = e & 15;
            const int off = (row << 6) + (((c4 >> 1) ^ (row & 7)) << 3) + (c4 & 1) * 4;
            const float4 xv = *(const float4*)&x[(size_t)(s0 + row) * DM + c4 * 4];
            s16x4 px; px.x = (short)f2b(xv.x); px.y = (short)f2b(xv.y);
            px.z = (short)f2b(xv.z); px.w = (short)f2b(xv.w);
            *(s16x4*)&At0[off] = px;
            const float4 wv = *(const float4*)&Wf[(size_t)(n0 + row) * DM + c4 * 4];
            s16x4 pw; pw.x = (short)f2b(wv.x); pw.y = (short)f2b(wv.y);
            pw.z = (short)f2b(wv.z); pw.w = (short)f2b(wv.w);
            *(s16x4*)&Bt0[off] = pw;
        }
    }
    __syncthreads();

    for (int kt = 0; kt < 12; ++kt) {
        if (fast && kt < 11) {               // issue next-chunk loads EARLY
            const int k0n = (kt + 1) * 64;
            #pragma unroll
            for (int i = 0; i < 4; ++i) {
                const int s = t + i * 256, row = s >> 3, bp = s & 7, blk = bp ^ (row & 7);
                areg[i] = *(const bf16x8*)&xb[(size_t)(s0 + row) * DM + k0n + blk * 8];
                breg[i] = *(const bf16x8*)&Wb[(size_t)(n0 + row) * DM + k0n + blk * 8];
            }
        }
        const unsigned short* Ab = (kt & 1) ? At1 : At0;
        const unsigned short* Bb = (kt & 1) ? Bt1 : Bt0;

        bf16x8 aA[4][2], bB[4][2];
        #pragma unroll
        for (int i = 0; i < 4; ++i)
            #pragma unroll
            for (int hh = 0; hh < 2; ++hh) {
                aA[i][hh] = *(const bf16x8*)&Ab[SWZ(m0 + 16 * i + l16, 4 * hh + quad)];
                bB[i][hh] = *(const bf16x8*)&Bb[SWZ(nn0 + 16 * i + l16, 4 * hh + quad)];
            }
        #pragma unroll
        for (int hh = 0; hh < 2; ++hh)
            #pragma unroll
            for (int i = 0; i < 4; ++i)
                #pragma unroll
                for (int j = 0; j < 4; ++j)
                    acc[i][j] = MFMA(aA[i][hh], bB[j][hh], acc[i][j]);

        if (kt < 11) {
            unsigned short* An = ((kt + 1) & 1) ? At1 : At0;
            unsigned short* Bn = ((kt + 1) & 1) ? Bt1 : Bt0;
            if (fast) {                      // vmcnt wait lands here
                #pragma unroll
                for (int i = 0; i < 4; ++i) {
                    const int s = t + i * 256, row = s >> 3, bp = s & 7;
                    *(bf16x8*)&An[row * 64 + bp * 8] = areg[i];
                    *(bf16x8*)&Bn[row * 64 + bp * 8] = breg[i];
                }
            } else {
                const int k0n = (kt + 1) * 64;
                for (int e = t; e < 2048; e += 256) {
                    const int row = e >> 4, c4 = e & 15;
                    const int off = (row << 6) + (((c4 >> 1) ^ (row & 7)) << 3) + (c4 & 1) * 4;
                    const float4 xv = *(const float4*)&x[(size_t)(s0 + row) * DM + k0n + c4 * 4];
                    s16x4 px; px.x = (short)f2b(xv.x); px.y = (short)f2b(xv.y);
                    px.z = (short)f2b(xv.z); px.w = (short)f2b(xv.w);
                    *(s16x4*)&An[off] = px;
                    const float4 wv = *(const float4*)&Wf[(size_t)(n0 + row) * DM + k0n + c4 * 4];
                    s16x4 pw; pw.x = (short)f2b(wv.x); pw.y = (short)f2b(wv.y);
                    pw.z = (short)f2b(wv.z); pw.w = (short)f2b(wv.w);
                    *(s16x4*)&Bn[off] = pw;
                }
            }
        }
        __syncthreads();
    }

    // ---- epilogue ----
    if (region <= 1) {
        // RoPE: pair (2fi,2fi+1) = adjacent cols = lanes l16, l16^1 (same quad).
        unsigned short* dst = (region == 0) ? Qo : Ko;
        const float qsc = (region == 0) ? 0.18033688011112042f : 1.0f;   // 0.125*log2e
        #pragma unroll
        for (int i = 0; i < 4; ++i)
            #pragma unroll
            for (int j = 0; j < 4; ++j)
                #pragma unroll
                for (int r = 0; r < 4; ++r) {
                    const int srow = s0 + m0 + 16 * i + 4 * quad + r;
                    const int n = n0 + nn0 + 16 * j + l16;
                    const int h = n >> 6, d = n & 63, fi = d >> 1;
                    const float own = acc[i][j][r] * qsc;
                    const float oth = __shfl_xor(own, 1);
                    float cs, sn;
                    if (fast) {
                        const float2 t2 = rope[srow * 32 + fi];
                        cs = t2.x; sn = t2.y;
                    } else {
                        const float invf = expf(-(float)fi * 0.28782313662425576f);
                        sincosf((float)srow * invf, &sn, &cs);
                    }
                    const float val = (d & 1) ? (oth * sn + own * cs)
                                              : (own * cs - oth * sn);
                    dst[(size_t)h * SEQ * HD + (size_t)srow * HD +
                        ((d & 1) ? 32 : 0) + fi] = f2b(val);
                }
    } else {
        // V: transpose the 128x128 tile via LDS (stride 130), packed b32 out.
        unsigned short* VL = SMEM;           // 128 x 130 ushorts = 33,280 B
        #pragma unroll
        for (int i = 0; i < 4; ++i)
            #pragma unroll
            for (int j = 0; j < 4; ++j)
                #pragma unroll
                for (int r = 0; r < 4; ++r)
                    VL[(nn0 + 16 * j + l16) * 130 + m0 + 16 * i + 4 * quad + r] =
                        f2b(acc[i][j][r]);
        __syncthreads();
        for (int e = t; e < 8192; e += 256) {
            const int dl = e >> 6, sp = e & 63;    // dl: local col, sp: seq pair
            const unsigned int v = (unsigned int)VL[dl * 130 + 2 * sp] |
                                   ((unsigned int)VL[dl * 130 + 2 * sp + 1] << 16);
            const int n = n0 + dl, h = n >> 6, d = n & 63;
            *(unsigned int*)&Vo[(size_t)h * SEQ * HD + (size_t)d * SEQ + s0 + 2 * sp] = v;
        }
    }
}

// ---------------------------------------------------------------------------
// K2: causal flash attention — round 10 version (measured best).
// ---------------------------------------------------------------------------
__global__ __launch_bounds__(256, 2) void attn_mfma(
    const unsigned short* __restrict__ Q,    // [h][seq][64], pre-scaled
    const unsigned short* __restrict__ K,    // [h][seq][64]
    const unsigned short* __restrict__ V,    // [h][64][seq]  (transposed)
    unsigned short* __restrict__ O,          // [4096][768]
    float* __restrict__ Part)                // [384][2][4160] fp32 partials
{
    __shared__ __align__(16) unsigned char SM[53248];
    unsigned short* Kst = (unsigned short*)SM;             // 128x64 SWZ, 16KB
    unsigned short* Vt  = (unsigned short*)(SM + 16384);   // 64x128 SWZ16, 16KB
    unsigned short* Ps  = (unsigned short*)(SM + 32768);   // 4 strips 64x40, 20KB
    float* ACC  = (float*)SM;
    float* ACC2 = (float*)(SM + 32768);
    float* Lx   = (float*)(SM + 51200);

    const int h  = blockIdx.y;
    const int xx = blockIdx.x;
    int i, kstart, nch, domask, partial, pslice;
    if (gridDim.x == 96) {
        if (xx < 64) {
            i = 63 - xx; kstart = 0;
            const int full = ((i * 64 + 63) >> 7) + 1;
            nch = full < 16 ? full : 16;
            domask  = (i <= 31);
            partial = (i >= 32); pslice = 0;
        } else {
            i = 127 - xx; kstart = 2048;
            nch = ((i * 64 + 63 - 2048) >> 7) + 1;
            domask = 1; partial = 1; pslice = 1;
        }
    } else {
        i = 63 - xx; kstart = 0;
        nch = ((i * 64 + 63) >> 7) + 1;
        domask = 1; partial = 0; pslice = 0;
    }
    const int q0 = i * 64;

    const int t    = threadIdx.x;
    const int w    = t >> 6;
    const int lane = t & 63;
    const int quad = lane >> 4;
    const int l16  = lane & 15;
    const size_t headoff = (size_t)h * SEQ * HD;

    for (int e = t; e < 512; e += 256) {
        const int row = e >> 3, bp = e & 7, blk = bp ^ (row & 7);
        *(bf16x8*)&Kst[row * 64 + bp * 8] =
            *(const bf16x8*)&Q[headoff + (size_t)(q0 + row) * HD + blk * 8];
    }
    __syncthreads();
    bf16x8 aQ[4][2];
    #pragma unroll
    for (int qt = 0; qt < 4; ++qt)
        #pragma unroll
        for (int hh = 0; hh < 2; ++hh)
            aQ[qt][hh] = *(const bf16x8*)&Kst[SWZ(16 * qt + l16, 4 * hh + quad)];
    __syncthreads();

    bf16x8 kreg[4], vreg[4];
    #pragma unroll
    for (int ii = 0; ii < 4; ++ii) {
        const int e = t + ii * 256, row = e >> 3, bp = e & 7, blk = bp ^ (row & 7);
        kreg[ii] = *(const bf16x8*)&K[headoff + (size_t)(kstart + row) * HD + blk * 8];
    }
    #pragma unroll
    for (int ii = 0; ii < 4; ++ii) {
        const int e = t + ii * 256, row = e >> 4, bp = e & 15, blk = bp ^ (row & 15);
        vreg[ii] = *(const bf16x8*)&V[headoff + (size_t)row * SEQ + kstart + blk * 8];
    }
    #pragma unroll
    for (int ii = 0; ii < 4; ++ii) {
        const int e = t + ii * 256, row = e >> 3, bp = e & 7;
        *(bf16x8*)&Kst[row * 64 + bp * 8] = kreg[ii];
    }
    #pragma unroll
    for (int ii = 0; ii < 4; ++ii) {
        const int e = t + ii * 256, row = e >> 4, bp = e & 15;
        *(bf16x8*)&Vt[row * 128 + bp * 8] = vreg[ii];
    }
    __syncthreads();

    bf16x8 ones;
    #pragma unroll
    for (int ii = 0; ii < 8; ++ii) ones[ii] = (short)0x3F80;

    f32x4 oT[4][4];
    #pragma unroll
    for (int dt = 0; dt < 4; ++dt)
        #pragma unroll
        for (int qt = 0; qt < 4; ++qt) oT[dt][qt] = (f32x4){0,0,0,0};
    f32x4 lT[4] = {{0,0,0,0},{0,0,0,0},{0,0,0,0},{0,0,0,0}};

    unsigned short* usp = Ps + w * 2560;

    for (int c = 0; c < nch; ++c) {
        const int k0 = kstart + c * 128;

        f32x4 sC[4][2];
        #pragma unroll
        for (int qt = 0; qt < 4; ++qt)
            #pragma unroll
            for (int kt = 0; kt < 2; ++kt) sC[qt][kt] = (f32x4){0,0,0,0};
        #pragma unroll
        for (int kt = 0; kt < 2; ++kt) {
            const int krow = 32 * w + 16 * kt + l16;
            #pragma unroll
            for (int hh = 0; hh < 2; ++hh) {
                const bf16x8 bK = *(const bf16x8*)&Kst[SWZ(krow, 4 * hh + quad)];
                #pragma unroll
                for (int qt = 0; qt < 4; ++qt)
                    sC[qt][kt] = MFMA(aQ[qt][hh], bK, sC[qt][kt]);
            }
        }

        if (c < nch - 1) {
            const int kn = k0 + 128;
            #pragma unroll
            for (int ii = 0; ii < 4; ++ii) {
                const int e = t + ii * 256, row = e >> 3, bp = e & 7, blk = bp ^ (row & 7);
                kreg[ii] = *(const bf16x8*)&K[headoff + (size_t)(kn + row) * HD + blk * 8];
            }
            #pragma unroll
            for (int ii = 0; ii < 4; ++ii) {
                const int e = t + ii * 256, row = e >> 4, bp = e & 15, blk = bp ^ (row & 15);
                vreg[ii] = *(const bf16x8*)&V[headoff + (size_t)row * SEQ + kn + blk * 8];
            }
        }

        if (domask && c == nch - 1) {
            #pragma unroll
            for (int kt = 0; kt < 2; ++kt) {
                const int key = k0 + 32 * w + 16 * kt + l16;
                #pragma unroll
                for (int qt = 0; qt < 4; ++qt)
                    #pragma unroll
                    for (int r = 0; r < 4; ++r)
                        if (key > q0 + 16 * qt + 4 * quad + r) sC[qt][kt][r] = -1e30f;
            }
        }

        #pragma unroll
        for (int qt = 0; qt < 4; ++qt)
            #pragma unroll
            for (int kt = 0; kt < 2; ++kt)
                #pragma unroll
                for (int r = 0; r < 4; ++r)
                    usp[(16 * qt + 4 * quad + r) * 40 + 16 * kt + l16] =
                        f2b(EXP2(sC[qt][kt][r]));
        asm volatile("s_waitcnt lgkmcnt(0)" ::: "memory");

        bf16x8 aV[4];
        #pragma unroll
        for (int dt = 0; dt < 4; ++dt) {
            const int row = 16 * dt + l16;
            aV[dt] = *(const bf16x8*)&Vt[row * 128 + (((4 * w + quad) ^ (row & 15)) << 3)];
        }
        #pragma unroll
        for (int qt = 0; qt < 4; ++qt) {
            const bf16x8 bP = *(const bf16x8*)&usp[(16 * qt + l16) * 40 + quad * 8];
            lT[qt] = MFMA(ones, bP, lT[qt]);
            #pragma unroll
            for (int dt = 0; dt < 4; ++dt)
                oT[dt][qt] = MFMA(aV[dt], bP, oT[dt][qt]);
        }

        __syncthreads();
        if (c < nch - 1) {
            #pragma unroll
            for (int ii = 0; ii < 4; ++ii) {
                const int e = t + ii * 256, row = e >> 3, bp = e & 7;
                *(bf16x8*)&Kst[row * 64 + bp * 8] = kreg[ii];
            }
            #pragma unroll
            for (int ii = 0; ii < 4; ++ii) {
                const int e = t + ii * 256, row = e >> 4, bp = e & 15;
                *(bf16x8*)&Vt[row * 128 + bp * 8] = vreg[ii];
            }
        }
        __syncthreads();
    }

    if (w != 0 && quad == 0) {
        #pragma unroll
        for (int qt = 0; qt < 4; ++qt)
            Lx[w * 64 + 16 * qt + l16] = lT[qt][0];
    }
    if (w == 1) {
        #pragma unroll
        for (int dt = 0; dt < 4; ++dt)
            #pragma unroll
            for (int qt = 0; qt < 4; ++qt)
                *(f32x4*)&ACC[(16 * qt + l16) * 72 + 16 * dt + 4 * quad] = oT[dt][qt];
    }
    __syncthreads();
    if (w == 0) {
        #pragma unroll
        for (int dt = 0; dt < 4; ++dt)
            #pragma unroll
            for (int qt = 0; qt < 4; ++qt)
                oT[dt][qt] += *(const f32x4*)&ACC[(16 * qt + l16) * 72 + 16 * dt + 4 * quad];
    }
    if (w == 2) {
        #pragma unroll
        for (int dt = 0; dt < 4; ++dt)
            #pragma unroll
            for (int qt = 0; qt < 4; ++qt)
                *(f32x4*)&ACC2[(16 * qt + l16) * 72 + 16 * dt + 4 * quad] = oT[dt][qt];
    }
    __syncthreads();
    if (w == 0) {
        #pragma unroll
        for (int dt = 0; dt < 4; ++dt)
            #pragma unroll
            for (int qt = 0; qt < 4; ++qt)
                oT[dt][qt] += *(const f32x4*)&ACC2[(16 * qt + l16) * 72 + 16 * dt + 4 * quad];
    }
    if (w == 3) {
        #pragma unroll
        for (int dt = 0; dt < 4; ++dt)
            #pragma unroll
            for (int qt = 0; qt < 4; ++qt)
                *(f32x4*)&ACC[(16 * qt + l16) * 72 + 16 * dt + 4 * quad] = oT[dt][qt];
    }
    __syncthreads();
    if (w == 0) {
        float ls[4];
        #pragma unroll
        for (int qt = 0; qt < 4; ++qt) {
            #pragma unroll
            for (int dt = 0; dt < 4; ++dt)
                oT[dt][qt] += *(const f32x4*)&ACC[(16 * qt + l16) * 72 + 16 * dt + 4 * quad];
            ls[qt] = lT[qt][0] + Lx[64 + 16 * qt + l16] +
                     Lx[128 + 16 * qt + l16] + Lx[192 + 16 * qt + l16];
        }
        if (!partial) {
            #pragma unroll
            for (int qt = 0; qt < 4; ++qt) {
                const float inv = 1.0f / ls[qt];
                const size_t rowoff = (size_t)(q0 + 16 * qt + l16) * DM + h * HD;
                #pragma unroll
                for (int dt = 0; dt < 4; ++dt) {
                    ushort4 u;
                    u.x = f2b(oT[dt][qt][0] * inv);
                    u.y = f2b(oT[dt][qt][1] * inv);
                    u.z = f2b(oT[dt][qt][2] * inv);
                    u.w = f2b(oT[dt][qt][3] * inv);
                    *(ushort4*)&O[rowoff + 16 * dt + 4 * quad] = u;
                }
            }
        } else {
            float* P = Part + (size_t)(((i - 32) * 12 + h) * 2 + pslice) * 4160;
            #pragma unroll
            for (int dt = 0; dt < 4; ++dt)
                #pragma unroll
                for (int qt = 0; qt < 4; ++qt)
                    *(f32x4*)&P[(16 * qt + l16) * 64 + 16 * dt + 4 * quad] = oT[dt][qt];
            if (quad == 0) {
                #pragma unroll
                for (int qt = 0; qt < 4; ++qt)
                    P[4096 + 16 * qt + l16] = ls[qt];
            }
        }
    }
}

// ---------------------------------------------------------------------------
// K2b: combine the two key-slices for q-tiles 32..63 — r10 version.
// ---------------------------------------------------------------------------
__global__ __launch_bounds__(256) void reduce_attn(
    const float* __restrict__ Part, unsigned short* __restrict__ O)
{
    const int b  = blockIdx.x;
    const int i  = 32 + b / 12, h = b % 12;
    const int q0 = i * 64;
    const float* P0 = Part + (size_t)(b * 2 + 0) * 4160;
    const float* P1 = Part + (size_t)(b * 2 + 1) * 4160;
    __shared__ float linv[64];
    const int t = threadIdx.x;
    if (t < 64) linv[t] = 1.0f / (P0[4096 + t] + P1[4096 + t]);
    __syncthreads();
    for (int idx = t; idx < 4096; idx += 256) {
        const int q = idx >> 6, d = idx & 63;
        const float v = (P0[q * 64 + d] + P1[q * 64 + d]) * linv[q];
        O[(size_t)(q0 + q) * DM + h * HD + d] = f2b(v);
    }
}

// ---------------------------------------------------------------------------
// K3: output projection with 128x128 tiles. Grid (32, 6). Same pipeline as
// qkv128; A (attention output) is always bf16; bias fused; fp32 out.
// ---------------------------------------------------------------------------
__global__ __launch_bounds__(256) void proj128(
    const unsigned short* __restrict__ A,    // [4096][768] bf16
    const float* __restrict__ Wo, const unsigned short* __restrict__ Wob,
    const float* __restrict__ bo,
    float* __restrict__ out, int fast)
{
    __shared__ __align__(16) unsigned short SMEM[32768];   // 64 KB
    unsigned short* At0 = SMEM;
    unsigned short* At1 = SMEM + 8192;
    unsigned short* Bt0 = SMEM + 16384;
    unsigned short* Bt1 = SMEM + 24576;

    const int t    = threadIdx.x;
    const int w    = t >> 6;
    const int lane = t & 63;
    const int quad = lane >> 4;
    const int l16  = lane & 15;
    const int s0 = blockIdx.x * 128;
    const int n0 = blockIdx.y * 128;
    const int m0  = 64 * (w & 1);
    const int nn0 = 64 * (w >> 1);

    f32x4 acc[4][4];
    #pragma unroll
    for (int i = 0; i < 4; ++i)
        #pragma unroll
        for (int j = 0; j < 4; ++j) acc[i][j] = (f32x4){0, 0, 0, 0};

    bf16x8 areg[4], breg[4];
    #pragma unroll
    for (int i = 0; i < 4; ++i) {
        const int s = t + i * 256, row = s >> 3, bp = s & 7, blk = bp ^ (row & 7);
        areg[i] = *(const bf16x8*)&A[(size_t)(s0 + row) * DM + blk * 8];
        if (fast) breg[i] = *(const bf16x8*)&Wob[(size_t)(n0 + row) * DM + blk * 8];
    }
    #pragma unroll
    for (int i = 0; i < 4; ++i) {
        const int s = t + i * 256, row = s >> 3, bp = s & 7;
        *(bf16x8*)&At0[row * 64 + bp * 8] = areg[i];
        if (fast) *(bf16x8*)&Bt0[row * 64 + bp * 8] = breg[i];
    }
    if (!fast) {
        for (int e = t; e < 2048; e += 256) {
            const int row = e >> 4, c4 = e & 15;
            const int off = (row << 6) + (((c4 >> 1) ^ (row & 7)) << 3) + (c4 & 1) * 4;
            const float4 wv = *(const float4*)&Wo[(size_t)(n0 + row) * DM + c4 * 4];
            s16x4 pw; pw.x = (short)f2b(wv.x); pw.y = (short)f2b(wv.y);
            pw.z = (short)f2b(wv.z); pw.w = (short)f2b(wv.w);
            *(s16x4*)&Bt0[off] = pw;
        }
    }
    __syncthreads();

    for (int kt = 0; kt < 12; ++kt) {
        if (kt < 11) {
            const int k0n = (kt + 1) * 64;
            #pragma unroll
            for (int i = 0; i < 4; ++i) {
                const int s = t + i * 256, row = s >> 3, bp = s & 7, blk = bp ^ (row & 7);
                areg[i] = *(const bf16x8*)&A[(size_t)(s0 + row) * DM + k0n + blk * 8];
                if (fast) breg[i] = *(const bf16x8*)&Wob[(size_t)(n0 + row) * DM + k0n + blk * 8];
            }
        }
        const unsigned short* Ab = (kt & 1) ? At1 : At0;
        const unsigned short* Bb = (kt & 1) ? Bt1 : Bt0;

        bf16x8 aA[4][2], bB[4][2];
        #pragma unroll
        for (int i = 0; i < 4; ++i)
            #pragma unroll
            for (int hh = 0; hh < 2; ++hh) {
                aA[i][hh] = *(const bf16x8*)&Ab[SWZ(m0 + 16 * i + l16, 4 * hh + quad)];
                bB[i][hh] = *(const bf16x8*)&Bb[SWZ(nn0 + 16 * i + l16, 4 * hh + quad)];
            }
        #pragma unroll
        for (int hh = 0; hh < 2; ++hh)
            #pragma unroll
            for (int i = 0; i < 4; ++i)
                #pragma unroll
                for (int j = 0; j < 4; ++j)
                    acc[i][j] = MFMA(aA[i][hh], bB[j][hh], acc[i][j]);

        if (kt < 11) {
            unsigned short* An = ((kt + 1) & 1) ? At1 : At0;
            unsigned short* Bn = ((kt + 1) & 1) ? Bt1 : Bt0;
            #pragma unroll
            for (int i = 0; i < 4; ++i) {
                const int s = t + i * 256, row = s >> 3, bp = s & 7;
                *(bf16x8*)&An[row * 64 + bp * 8] = areg[i];
                if (fast) *(bf16x8*)&Bn[row * 64 + bp * 8] = breg[i];
            }
            if (!fast) {
                const int k0n = (kt + 1) * 64;
                for (int e = t; e < 2048; e += 256) {
                    const int row = e >> 4, c4 = e & 15;
                    const int off = (row << 6) + (((c4 >> 1) ^ (row & 7)) << 3) + (c4 & 1) * 4;
                    const float4 wv = *(const float4*)&Wo[(size_t)(n0 + row) * DM + k0n + c4 * 4];
                    s16x4 pw; pw.x = (short)f2b(wv.x); pw.y = (short)f2b(wv.y);
                    pw.z = (short)f2b(wv.z); pw.w = (short)f2b(wv.w);
                    *(s16x4*)&Bn[off] = pw;
                }
            }
        }
        __syncthreads();
    }

    #pragma unroll
    for (int i = 0; i < 4; ++i)
        #pragma unroll
        for (int j = 0; j < 4; ++j) {
            const int n = n0 + nn0 + 16 * j + l16;
            const float bv = bo[n];
            #pragma unroll
            for (int r = 0; r < 4; ++r) {
                const int srow = s0 + m0 + 16 * i + 4 * quad + r;
                out[(size_t)srow * DM + n] = acc[i][j][r] + bv;
            }
        }
}

// ---------------------------------------------------------------------------
extern "C" void kernel_launch(void* const* d_in, const int* in_sizes, int n_in,
                              void* d_out, int out_size, void* d_ws, size_t ws_size,
                              hipStream_t stream) {
    const float* x  = (const float*)d_in[0];
    const float* Wq = (const float*)d_in[2];
    const float* Wk = (const float*)d_in[3];
    const float* Wv = (const float*)d_in[4];
    const float* Wo = (const float*)d_in[5];
    const float* bo = (const float*)d_in[6];
    float* out = (float*)d_out;

    unsigned short* U  = (unsigned short*)d_ws;
    unsigned short* Qw = U;
    unsigned short* Kw = U + PER;
    unsigned short* Vw = U + 2 * PER;    // transposed [h][64][seq]
    unsigned short* Ow = U + 3 * PER;    // [4096][768]
    unsigned short* xb  = U + 4 * PER;
    unsigned short* Wqb = xb + XN;
    unsigned short* Wkb = Wqb + WN;
    unsigned short* Wvb = Wkb + WN;
    unsigned short* Wob = Wvb + WN;
    float2* rope = (float2*)(Wob + WN);  // [4096][32]
    float*  part = (float*)(rope + 4096 * 32);   // [384][2][4160] fp32
    const size_t need  = (char*)part - (char*)d_ws;
    const size_t need2 = need + (size_t)384 * 2 * 4160 * 4;
    const int fast  = (ws_size >= need)  ? 1 : 0;
    const int split = (ws_size >= need2) ? 1 : 0;

    if (fast)
        prep_kernel<<<1024, 256, 0, stream>>>(x, Wq, Wk, Wv, Wo, xb, rope);
    qkv128<<<dim3(SEQ / 128, 18), 256, 0, stream>>>(
        x, xb, Wq, Wk, Wv, Wqb, Wkb, Wvb, rope, Qw, Kw, Vw, fast);
    if (split) {
        attn_mfma<<<dim3(96, NH), 256, 0, stream>>>(Qw, Kw, Vw, Ow, part);
        reduce_attn<<<dim3(384), 256, 0, stream>>>(part, Ow);
    } else {
        attn_mfma<<<dim3(64, NH), 256, 0, stream>>>(Qw, Kw, Vw, Ow, part);
    }
    proj128<<<dim3(SEQ / 128, DM / 128), 256, 0, stream>>>(Ow, Wo, Wob, bo, out, fast);
}